// Round 16
// baseline (213.774 us; speedup 1.0000x reference)
//
#include <hip/hip_runtime.h>
#include <math.h>

// ---------------- problem constants ----------------
#define BB    8
#define NLEN  8192          // sequence length (FFT size)
#define CC    512           // channels
#define HH    8             // heads
#define DH    64            // head dim
#define MH    4096          // NLEN/2 (complex FFT size)
#define FREQ  4097          // rfft bins
#define FP    4160          // padded spectrum row stride (uint bins): 16640B = 65*256B
#define NSEQ  (BB*CC)       // 4096 rows

// scratch: two regions of NSEQ*FP uint (bf16 (r,i) packed bins)
#define REGION_BYTES ((size_t)NSEQ * FP * 4ull)

static __device__ __align__(256) unsigned char g_scratch[2ull * (size_t)NSEQ * FP * 4ull];
// prepped weights: [h][plane(0=w1r,1=w1i,2=w2r,3=w2i)][o][swizzled k-slot] bf16
__device__ unsigned short g_wprep[8 * 4 * 64 * 64];

typedef __attribute__((ext_vector_type(8))) short bf16x8;
typedef __attribute__((ext_vector_type(4))) float f32x4;
typedef __attribute__((ext_vector_type(4))) unsigned u32x4;

__device__ __forceinline__ f32x4 MFMA(bf16x8 a, bf16x8 b, f32x4 c){
  return __builtin_amdgcn_mfma_f32_16x16x32_bf16(a, b, c, 0, 0, 0);
}

__device__ __forceinline__ unsigned short f2bf(float f){
  unsigned u = __float_as_uint(f);
  return (unsigned short)((u + 0x7fffu + ((u >> 16) & 1u)) >> 16);
}
__device__ __forceinline__ unsigned pack2(float a, float b){
  return (unsigned)f2bf(a) | ((unsigned)f2bf(b) << 16);
}
__device__ __forceinline__ float bflo(unsigned u){ return __uint_as_float(u << 16); }
__device__ __forceinline__ float bfhi(unsigned u){ return __uint_as_float(u & 0xffff0000u); }

// cos/sin(2*pi*q/32) for q=0..15
__device__ const float C32C[16] = {
  1.f, 0.98078528f, 0.92387953f, 0.83146961f, 0.70710678f, 0.55557023f,
  0.38268343f, 0.19509032f, 0.f, -0.19509032f, -0.38268343f, -0.55557023f,
  -0.70710678f, -0.83146961f, -0.92387953f, -0.98078528f};
__device__ const float C32S[16] = {
  0.f, 0.19509032f, 0.38268343f, 0.55557023f, 0.70710678f, 0.83146961f,
  0.92387953f, 0.98078528f, 1.f, 0.98078528f, 0.92387953f, 0.83146961f,
  0.70710678f, 0.55557023f, 0.38268343f, 0.19509032f};

// fast exact-enough GELU: Abramowitz-Stegun 7.1.26 erf (max err 1.5e-7)
__device__ __forceinline__ float gelu_fast(float v){
  float x  = v * 0.70710678118654752440f;
  float ax = fabsf(x);
  float t  = __builtin_amdgcn_rcpf(fmaf(0.3275911f, ax, 1.0f));
  float p  = fmaf(fmaf(fmaf(fmaf(1.061405429f, t, -1.453152027f), t,
                            1.421413741f), t, -0.284496736f), t, 0.254829592f);
  float e  = __expf(-x * x);
  float erf_ax = fmaf(-p * t, e, 1.0f);
  float erfx = copysignf(erf_ax, x);
  return 0.5f * v * (1.0f + erfx);
}

// ---------------- complex helpers ----------------
__device__ __forceinline__ float2 cadd(float2 a, float2 b){ return make_float2(a.x+b.x, a.y+b.y); }
__device__ __forceinline__ float2 csub(float2 a, float2 b){ return make_float2(a.x-b.x, a.y-b.y); }
__device__ __forceinline__ float2 cmul(float2 a, float2 b){
  return make_float2(fmaf(a.x, b.x, -(a.y*b.y)), fmaf(a.x, b.y, a.y*b.x));
}

// ---------------- transpose 1: x [B][N][C] fp32 -> xt [B][C][N] bf16 ----------------
__global__ __launch_bounds__(256) void transpose_in_k(const float* __restrict__ in,
                                                      unsigned* __restrict__ out){
  __shared__ float tile[64][33];
  int b  = blockIdx.z;
  int c0 = blockIdx.x * 32;
  int n0 = blockIdx.y * 64;
  int t  = threadIdx.x;
  int tx = t & 31, ty = t >> 5;
  const float* src = in + ((size_t)b * NLEN + n0) * CC + c0;
  #pragma unroll
  for (int k = 0; k < 8; ++k)
    tile[ty + 8*k][tx] = src[(size_t)(ty + 8*k) * CC + tx];
  __syncthreads();
  int lt = t & 15;
  int nl = 4 * lt;
  #pragma unroll
  for (int kk = 0; kk < 2; ++kk){
    int cl = (t >> 4) + 16*kk;
    uint2 u;
    u.x = pack2(tile[nl    ][cl], tile[nl + 1][cl]);
    u.y = pack2(tile[nl + 2][cl], tile[nl + 3][cl]);
    *(uint2*)(out + ((size_t)(b * CC + c0 + cl) * NLEN + n0) / 2 + 2*lt) = u;
  }
}

// ---------------- transpose 2: yt [B][C][N] bf16 -> out [B][N][C] fp32 ----------------
__global__ __launch_bounds__(256) void transpose_out_k(const unsigned* __restrict__ in,
                                                       float* __restrict__ out){
  __shared__ float tile[64][33];
  int b  = blockIdx.z;
  int c0 = blockIdx.x * 32;
  int n0 = blockIdx.y * 64;
  int t  = threadIdx.x;
  int lt = t & 15;
  int nl = 4 * lt;
  #pragma unroll
  for (int kk = 0; kk < 2; ++kk){
    int cl = (t >> 4) + 16*kk;
    uint2 u = *(const uint2*)(in + ((size_t)(b * CC + c0 + cl) * NLEN + n0) / 2 + 2*lt);
    tile[nl    ][cl] = bflo(u.x);
    tile[nl + 1][cl] = bfhi(u.x);
    tile[nl + 2][cl] = bflo(u.y);
    tile[nl + 3][cl] = bfhi(u.y);
  }
  __syncthreads();
  int tx = t & 31, ty = t >> 5;
  float* dst = out + ((size_t)b * NLEN + n0) * CC + c0;
  #pragma unroll
  for (int k = 0; k < 8; ++k)
    dst[(size_t)(ty + 8*k) * CC + tx] = tile[ty + 8*k][tx];
}

// ================= radix-16 register FFT (N=4096, 256 threads, 3 passes) =================
#define SL(e) ((e) + ((e) >> 4))
#define PERM16(p) ((((p) & 3) << 2) | ((p) >> 2))   // X[p] lives in v[PERM16(p)] after dft16ip

template<int SIGN>
__device__ __forceinline__ void dft4ip(float2& v0, float2& v1, float2& v2, float2& v3){
  float2 s02 = cadd(v0, v2), d02 = csub(v0, v2);
  float2 s13 = cadd(v1, v3), d13 = csub(v1, v3);
  float2 id = make_float2(-(float)SIGN * d13.y, (float)SIGN * d13.x);
  v0 = cadd(s02, s13);
  v1 = cadd(d02, id);
  v2 = csub(s02, s13);
  v3 = csub(d02, id);
}

template<int SIGN>
__device__ __forceinline__ float2 w16c(int m){   // e^{SIGN*2pi*i*m/16}
  const float c1 = 0.9238795325112867f, s1 = 0.3826834323650898f, r = 0.7071067811865476f;
  float cs = 1.f, sn = 0.f;
  if (m == 1){ cs = c1;  sn = s1; }
  else if (m == 2){ cs = r;   sn = r; }
  else if (m == 3){ cs = s1;  sn = c1; }
  else if (m == 4){ cs = 0.f; sn = 1.f; }
  else if (m == 6){ cs = -r;  sn = r; }
  else if (m == 9){ cs = -c1; sn = -s1; }
  return make_float2(cs, (float)SIGN * sn);
}

template<int SIGN>
__device__ __forceinline__ void dft16ip(float2 v[16]){
  #pragma unroll
  for (int q0 = 0; q0 < 4; ++q0) dft4ip<SIGN>(v[q0], v[q0+4], v[q0+8], v[q0+12]);
  #pragma unroll
  for (int p0 = 0; p0 < 4; ++p0)
    #pragma unroll
    for (int q0 = 0; q0 < 4; ++q0){
      const int m = p0 * q0;
      if (m) v[q0 + 4*p0] = cmul(v[q0 + 4*p0], w16c<SIGN>(m));
    }
  #pragma unroll
  for (int p0 = 0; p0 < 4; ++p0) dft4ip<SIGN>(v[4*p0], v[4*p0+1], v[4*p0+2], v[4*p0+3]);
}

// 1 sincos + log-depth power tree
template<int SIGN>
__device__ __forceinline__ void twiddle16(float2 v[16], int jm, float invRNs){
  float ang = (float)SIGN * 6.2831853071795864769f * (float)jm * invRNs;
  float sn, cs; __sincosf(ang, &sn, &cs);
  float2 tw[16];
  tw[1] = make_float2(cs, sn);
  #pragma unroll
  for (int q = 2; q < 16; ++q) tw[q] = cmul(tw[q >> 1], tw[q - (q >> 1)]);
  #pragma unroll
  for (int q = 1; q < 16; ++q) v[q] = cmul(v[q], tw[q]);
}

template<int SIGN, int NS>
__device__ __forceinline__ void fft_mid_pass(float2* lds2, float2 v[16], int t){
  #pragma unroll
  for (int q = 0; q < 16; ++q) v[q] = lds2[SL(t + 256*q)];
  int jm = t & (NS - 1);
  if (NS > 1) twiddle16<SIGN>(v, jm, 1.0f / (16.0f * (float)NS));   // NS==1: twiddle == 1
  dft16ip<SIGN>(v);
  __syncthreads();
  int base = ((t - jm) << 4) + jm;
  #pragma unroll
  for (int p = 0; p < 16; ++p) lds2[SL(base + p*NS)] = v[PERM16(p)];
  __syncthreads();
}

#define ORTHO_S 0.011048543456039806f   // 1/sqrt(8192)

// ---------------- forward rfft-8192: xt bf16 row -> spec bf16 bins ----------------
__global__ __launch_bounds__(256) void fft_fwd_k(const unsigned* __restrict__ xt,
                                                 unsigned* __restrict__ spec){
  __shared__ float2 lds2[4352];
  int t = threadIdx.x;
  size_t row = blockIdx.x;
  const unsigned* src = xt + row * (NLEN/2);
  float2 v[16];
  #pragma unroll
  for (int q = 0; q < 16; ++q){
    unsigned u = src[t + 256*q];
    v[q] = make_float2(bflo(u), bfhi(u));   // z[m] = x[2m] + i x[2m+1]
  }
  dft16ip<-1>(v);
  #pragma unroll
  for (int p = 0; p < 16; ++p) lds2[SL(16*t + p)] = v[PERM16(p)];
  __syncthreads();
  fft_mid_pass<-1, 16 >(lds2, v, t);
  fft_mid_pass<-1, 256>(lds2, v, t);
  // Hermitian-pair unpack: bins k and 4096-k from one (Zk, Z(M-k)) pair + one twiddle.
  unsigned* dst = spec + row * (size_t)FP;
  float snb, csb;
  __sincosf(-6.2831853071795864769f * (float)t / (float)NLEN, &snb, &csb);
  #pragma unroll
  for (int q = 0; q < 8; ++q){
    int k = t + 256*q;                       // [0, 2048)
    float2 zk = lds2[SL(k)];
    float2 zc = lds2[SL((MH - k) & (MH - 1))];
    float ex = 0.5f*(zk.x + zc.x);
    float ey = 0.5f*(zk.y - zc.y);
    float ox =  0.5f*(zk.y + zc.y);
    float oy = -0.5f*(zk.x - zc.x);
    float cs = fmaf(csb, C32C[q],  snb*C32S[q]);
    float sn = fmaf(snb, C32C[q], -csb*C32S[q]);
    float P = cs*ox - sn*oy;
    float Q = cs*oy + sn*ox;
    dst[k]      = pack2(ORTHO_S*(ex + P), ORTHO_S*(ey + Q));
    dst[MH - k] = pack2(ORTHO_S*(ex - P), ORTHO_S*(Q - ey));   // k=0 -> Nyquist bin 4096
  }
  if (t == 0){                               // self-dual bin 2048: X = (Zx, -Zy)
    float2 zm = lds2[SL(2048)];
    dst[2048] = pack2(ORTHO_S*zm.x, -ORTHO_S*zm.y);
  }
}

// ---------------- inverse rfft-8192: spec bf16 bins -> yt bf16 row ----------------
// Hermitian-pair prep (one pair load -> Z[k] and Z[4096-k]); member-access epilogue.
__global__ __launch_bounds__(256) void fft_inv_k(const unsigned* __restrict__ spec,
                                                 unsigned* __restrict__ yt){
  __shared__ float2 lds2[4352];
  int t = threadIdx.x;
  size_t row = blockIdx.x;
  const unsigned* src = spec + row * (size_t)FP;
  float snb, csb;
  __sincosf(6.2831853071795864769f * (float)t / (float)NLEN, &snb, &csb);
  #pragma unroll
  for (int q = 0; q < 8; ++q){
    int k = t + 256*q;                       // [0, 2048)
    unsigned uk = src[k];
    unsigned uc = src[MH - k];               // k=0 -> Nyquist bin 4096
    float2 xk = make_float2(bflo(uk), bfhi(uk));
    float2 xc = make_float2(bflo(uc), bfhi(uc));
    if (k == 0){ xk.y = 0.0f; xc.y = 0.0f; } // drop imag at DC/Nyquist
    float ex = xk.x + xc.x;
    float ey = xk.y - xc.y;
    float dx = xk.x - xc.x;
    float dy = xk.y + xc.y;
    float cs = fmaf(csb, C32C[q], -snb*C32S[q]);
    float sn = fmaf(snb, C32C[q],  csb*C32S[q]);
    float ox = cs*dx - sn*dy;
    float oy = cs*dy + sn*dx;
    lds2[SL(k)] = make_float2(ex - oy, ey + ox);          // Z[k] = E + iO
    if (k > 0)
      lds2[SL(MH - k)] = make_float2(ex + oy, ox - ey);   // Z[4096-k] = conj(E - iO)
  }
  if (t == 0){                               // self-dual m=2048: Z = 2*conj(X[2048])
    unsigned um = src[2048];
    lds2[SL(2048)] = make_float2(2.0f*bflo(um), -2.0f*bfhi(um));
  }
  __syncthreads();
  float2 v[16];
  fft_mid_pass<1, 1  >(lds2, v, t);          // pass 1 (no twiddle)
  fft_mid_pass<1, 16 >(lds2, v, t);
  fft_mid_pass<1, 256>(lds2, v, t);
  // wide-store epilogue
  uint4* d4 = (uint4*)(yt + row * (NLEN/2) + 16*t);
  #pragma unroll
  for (int g = 0; g < 4; ++g){
    float2 w0 = lds2[SL(16*t + 4*g    )];
    float2 w1 = lds2[SL(16*t + 4*g + 1)];
    float2 w2 = lds2[SL(16*t + 4*g + 2)];
    float2 w3 = lds2[SL(16*t + 4*g + 3)];
    uint4 stv;
    stv.x = pack2(ORTHO_S*w0.x, ORTHO_S*w0.y);
    stv.y = pack2(ORTHO_S*w1.x, ORTHO_S*w1.y);
    stv.z = pack2(ORTHO_S*w2.x, ORTHO_S*w2.y);
    stv.w = pack2(ORTHO_S*w3.x, ORTHO_S*w3.y);
    d4[g] = stv;
  }
}

// ---------------- weight prep: transpose + bf16 + swizzle (+pi for W2) ----------------
__global__ __launch_bounds__(256) void wprep_k(const float* __restrict__ w1,
                                               const float* __restrict__ w2){
  int t = threadIdx.x;
  int h = blockIdx.x;
  #pragma unroll 4
  for (int u = 0; u < 64; ++u){
    int idx = t + 256*u;          // p*4096 + o*64 + jj
    int p = idx >> 12;
    int o = (idx >> 6) & 63;
    int jj = idx & 63;
    int swo = (o ^ (o >> 3)) & 7;
    int s = (((jj >> 3) ^ swo) << 3) | (jj & 7);   // linear k-slot
    int i;
    if (p < 2){
      i = s;
    } else {
      int ks = s >> 5, g = (s >> 3) & 3, j = s & 7;
      i = (2*ks + (j >> 2))*16 + 4*g + (j & 3);
    }
    const float* src = (p < 2) ? w1 : w2;
    float v = src[(size_t)(p & 1) * 32768 + (size_t)h * 4096 + i * 64 + o];
    g_wprep[(size_t)h * 16384 + idx] = f2bf(v);
  }
}

// ---------------- middle: BARRIER-FREE, LDS-FREE MFMA MLP ----------------
// W fragments read per-wave directly from L2-hot g_wprep into VGPRs; X direct from
// global. Zero __syncthreads, zero LDS -> waves fully independent for latency hiding.
__global__ __launch_bounds__(256) void afno_mid_mfma_k(const unsigned* __restrict__ spec_in,
                                                       unsigned* __restrict__ spec_out,
                                                       const float* __restrict__ b1,
                                                       const float* __restrict__ b2){
  const int t = threadIdx.x;
  const int bx = blockIdx.x, h = blockIdx.y, b = blockIdx.z;
  const int F0 = bx * 64;
  const size_t rowbase = ((size_t)b * HH + h) * DH;
  const int l = t & 63, wv = t >> 6;
  const int lf = l & 15, lg = l >> 4;
  const int wf0 = wv * 16;
  const unsigned short* __restrict__ gW = g_wprep + (size_t)h * 16384;

  // ---- issue X fragment loads first ----
  int f = F0 + wf0 + lf;
  int fc = (f < FP) ? f : (FP - 1);                      // clamp; results masked at store
  const unsigned* xcol = spec_in + rowbase * (size_t)FP + fc;
  unsigned bins[16];
  #pragma unroll
  for (int ks = 0; ks < 2; ++ks){
    int i0 = (ks*4 + lg) * 8;
    #pragma unroll
    for (int j = 0; j < 8; ++j)
      bins[ks*8 + j] = xcol[(i0 + j) * FP];
  }

  // ---- stage-1 W fragments into VGPRs (L2-hot broadcast reads) ----
  bf16x8 w1r[2][4], w1i[2][4];
  #pragma unroll
  for (int ks = 0; ks < 2; ++ks){
    int b0 = ks*4 + lg;
    #pragma unroll
    for (int mt = 0; mt < 4; ++mt){
      int o = mt*16 + lf;
      int swo = (o ^ (o >> 3)) & 7;
      int off = o*64 + ((b0 ^ swo) << 3);
      w1r[ks][mt] = *(const bf16x8*)(gW + off);          // W1R
      w1i[ks][mt] = *(const bf16x8*)(gW + 4096 + off);   // W1I
    }
  }

  // ---- hoist biases ----
  float4 br1[4], bi1[4];
  #pragma unroll
  for (int mt = 0; mt < 4; ++mt){
    br1[mt] = *(const float4*)(b1 +       (size_t)h*64 + mt*16 + lg*4);
    bi1[mt] = *(const float4*)(b1 + 512 + (size_t)h*64 + mt*16 + lg*4);
  }
  float b2r[4], b2i[4];
  #pragma unroll
  for (int nt = 0; nt < 4; ++nt){
    b2r[nt] = b2[(size_t)h*64 + nt*16 + lf];
    b2i[nt] = b2[512 + (size_t)h*64 + nt*16 + lf];
  }

  const f32x4 zz = {0.f, 0.f, 0.f, 0.f};
  f32x4 a1R[4], a1I[4];
  #pragma unroll
  for (int mt = 0; mt < 4; ++mt){ a1R[mt] = zz; a1I[mt] = zz; }

  // -------- stage 1: O1^T = W1^T X^T (all operands in registers) --------
  #pragma unroll
  for (int ks = 0; ks < 2; ++ks){
    u32x4 pr, pi;
    pr.x = __builtin_amdgcn_perm(bins[ks*8+1], bins[ks*8+0], 0x05040100u);
    pr.y = __builtin_amdgcn_perm(bins[ks*8+3], bins[ks*8+2], 0x05040100u);
    pr.z = __builtin_amdgcn_perm(bins[ks*8+5], bins[ks*8+4], 0x05040100u);
    pr.w = __builtin_amdgcn_perm(bins[ks*8+7], bins[ks*8+6], 0x05040100u);
    pi.x = __builtin_amdgcn_perm(bins[ks*8+1], bins[ks*8+0], 0x07060302u);
    pi.y = __builtin_amdgcn_perm(bins[ks*8+3], bins[ks*8+2], 0x07060302u);
    pi.z = __builtin_amdgcn_perm(bins[ks*8+5], bins[ks*8+4], 0x07060302u);
    pi.w = __builtin_amdgcn_perm(bins[ks*8+7], bins[ks*8+6], 0x07060302u);
    bf16x8 bxr = __builtin_bit_cast(bf16x8, pr);
    bf16x8 bxi = __builtin_bit_cast(bf16x8, pi);
    #pragma unroll
    for (int mt = 0; mt < 4; ++mt){
      bf16x8 awin = w1i[ks][mt] ^ (short)0x8000;
      a1R[mt] = MFMA(w1r[ks][mt], bxr, a1R[mt]);
      a1R[mt] = MFMA(awin,        bxi, a1R[mt]);
      a1I[mt] = MFMA(w1i[ks][mt], bxr, a1I[mt]);
      a1I[mt] = MFMA(w1r[ks][mt], bxi, a1I[mt]);
    }
  }

  // ---- stage-2 W fragments (loaded now; stage-1 accs about to retire) ----
  bf16x8 w2r[2][4], w2i[2][4];
  #pragma unroll
  for (int ks = 0; ks < 2; ++ks){
    int b0 = ks*4 + lg;
    #pragma unroll
    for (int nt = 0; nt < 4; ++nt){
      int o2 = nt*16 + lf;
      int swo = (o2 ^ (o2 >> 3)) & 7;
      int off = o2*64 + ((b0 ^ swo) << 3);
      w2r[ks][nt] = *(const bf16x8*)(gW + 8192  + off);  // W2R
      w2i[ks][nt] = *(const bf16x8*)(gW + 12288 + off);  // W2I
    }
  }

  // -------- stage-1 epilogue: bias + GELU -> stage-2 A-fragments --------
  bf16x8 aFr[2], aFi[2], aFin[2];
  #pragma unroll
  for (int ks = 0; ks < 2; ++ks){
    const int m0 = 2*ks, m1 = 2*ks + 1;
    u32x4 wr4, wi4;
    wr4.x = pack2(gelu_fast(a1R[m0][0] + br1[m0].x), gelu_fast(a1R[m0][1] + br1[m0].y));
    wr4.y = pack2(gelu_fast(a1R[m0][2] + br1[m0].z), gelu_fast(a1R[m0][3] + br1[m0].w));
    wr4.z = pack2(gelu_fast(a1R[m1][0] + br1[m1].x), gelu_fast(a1R[m1][1] + br1[m1].y));
    wr4.w = pack2(gelu_fast(a1R[m1][2] + br1[m1].z), gelu_fast(a1R[m1][3] + br1[m1].w));
    wi4.x = pack2(gelu_fast(a1I[m0][0] + bi1[m0].x), gelu_fast(a1I[m0][1] + bi1[m0].y));
    wi4.y = pack2(gelu_fast(a1I[m0][2] + bi1[m0].z), gelu_fast(a1I[m0][3] + bi1[m0].w));
    wi4.z = pack2(gelu_fast(a1I[m1][0] + bi1[m1].x), gelu_fast(a1I[m1][1] + bi1[m1].y));
    wi4.w = pack2(gelu_fast(a1I[m1][2] + bi1[m1].z), gelu_fast(a1I[m1][3] + bi1[m1].w));
    aFr[ks]  = __builtin_bit_cast(bf16x8, wr4);
    aFi[ks]  = __builtin_bit_cast(bf16x8, wi4);
    aFin[ks] = aFi[ks] ^ (short)0x8000;
  }

  // -------- stage 2: O2 = O1 W2 --------
  f32x4 a2R[4], a2I[4];
  #pragma unroll
  for (int nt = 0; nt < 4; ++nt){ a2R[nt] = zz; a2I[nt] = zz; }
  #pragma unroll
  for (int ks = 0; ks < 2; ++ks){
    #pragma unroll
    for (int nt = 0; nt < 4; ++nt){
      a2R[nt] = MFMA(aFr[ks],  w2r[ks][nt], a2R[nt]);
      a2R[nt] = MFMA(aFin[ks], w2i[ks][nt], a2R[nt]);
      a2I[nt] = MFMA(aFi[ks],  w2r[ks][nt], a2I[nt]);
      a2I[nt] = MFMA(aFr[ks],  w2i[ks][nt], a2I[nt]);
    }
  }

  // -------- stage-2 epilogue: bias + wide 16B stores --------
  int f0 = F0 + wf0 + lg*4;
  if (f0 <= MH){
    #pragma unroll
    for (int nt = 0; nt < 4; ++nt){
      int o2 = nt*16 + lf;
      uint4 st;
      st.x = pack2(a2R[nt][0] + b2r[nt], a2I[nt][0] + b2i[nt]);
      st.y = pack2(a2R[nt][1] + b2r[nt], a2I[nt][1] + b2i[nt]);
      st.z = pack2(a2R[nt][2] + b2r[nt], a2I[nt][2] + b2i[nt]);
      st.w = pack2(a2R[nt][3] + b2r[nt], a2I[nt][3] + b2i[nt]);
      *(uint4*)(spec_out + (rowbase + o2) * (size_t)FP + f0) = st;
    }
  }
}

// ---------------- launch ----------------
extern "C" void kernel_launch(void* const* d_in, const int* in_sizes, int n_in,
                              void* d_out, int out_size, void* d_ws, size_t ws_size,
                              hipStream_t stream) {
  const float* x  = (const float*)d_in[0];
  const float* w1 = (const float*)d_in[1];
  const float* b1 = (const float*)d_in[2];
  const float* w2 = (const float*)d_in[3];
  const float* b2 = (const float*)d_in[4];
  float* out = (float*)d_out;

  unsigned char* base = (unsigned char*)d_ws;
  if (ws_size < 2 * REGION_BYTES){
    void* p = nullptr;
    hipGetSymbolAddress(&p, HIP_SYMBOL(g_scratch));
    base = (unsigned char*)p;
  }
  unsigned* specA = (unsigned*)base;                 // region A: spectrum1, later yt
  unsigned char* regB = base + REGION_BYTES;         // region B: xt, later spectrum2
  unsigned* xt    = (unsigned*)regB;
  unsigned* specB = (unsigned*)regB;
  unsigned* ytp   = (unsigned*)base;

  // 0) weight prep (bf16 + transpose + swizzle + stage-2 pi)
  wprep_k<<<8, 256, 0, stream>>>(w1, w2);
  // 1) transpose x [B][N][C] fp32 -> xt [B][C][N] bf16
  transpose_in_k<<<dim3(CC/32, NLEN/64, BB), 256, 0, stream>>>(x, xt);
  // 2) forward rfft per row (radix-16 register FFT, Hermitian-pair unpack)
  fft_fwd_k<<<NSEQ, 256, 0, stream>>>(xt, specA);
  // 3) complex MLP (bf16 MFMA; barrier-free, LDS-free, all-register operands)
  afno_mid_mfma_k<<<dim3(65, HH, BB), 256, 0, stream>>>(specA, specB, b1, b2);
  // 4) inverse rfft per row (Hermitian-pair prep, wide stores)
  fft_inv_k<<<NSEQ, 256, 0, stream>>>(specB, ytp);
  // 5) transpose yt [B][C][N] bf16 -> out [B][N][C] fp32
  transpose_out_k<<<dim3(CC/32, NLEN/64, BB), 256, 0, stream>>>(ytp, out);
}

// Round 17
// 205.457 us; speedup vs baseline: 1.0405x; 1.0405x over previous
//
#include <hip/hip_runtime.h>
#include <math.h>

// ---------------- problem constants ----------------
#define BB    8
#define NLEN  8192          // sequence length (FFT size)
#define CC    512           // channels
#define HH    8             // heads
#define DH    64            // head dim
#define MH    4096          // NLEN/2 (complex FFT size)
#define FREQ  4097          // rfft bins
#define FP    4160          // region-sizing row equivalent (65 tiles * 64)
#define NSEQ  (BB*CC)       // 4096 rows
#define BHSZ  (65*4096)     // uints per (b,h) group: 65 f-tiles x [i=64][f=64]

// spectrum layout: [b][h][ftile][i][f] bf16-pair bins; bin k of channel i lives at
// bh*BHSZ + (k>>6)*4096 + i*64 + (k&63)  -> mid reads/writes CONTIGUOUS 16KB tiles.
#define KADDR(k) ((((k) >> 6) << 12) + ((k) & 63))

// scratch: two regions of NSEQ*FP uint
#define REGION_BYTES ((size_t)NSEQ * FP * 4ull)

static __device__ __align__(256) unsigned char g_scratch[2ull * (size_t)NSEQ * FP * 4ull];
// prepped weights: [h][plane(0=w1r,1=w1i,2=w2r,3=w2i)][o][swizzled k-slot] bf16
__device__ unsigned short g_wprep[8 * 4 * 64 * 64];

typedef __attribute__((ext_vector_type(8))) short bf16x8;
typedef __attribute__((ext_vector_type(4))) float f32x4;
typedef __attribute__((ext_vector_type(4))) unsigned u32x4;

__device__ __forceinline__ f32x4 MFMA(bf16x8 a, bf16x8 b, f32x4 c){
  return __builtin_amdgcn_mfma_f32_16x16x32_bf16(a, b, c, 0, 0, 0);
}

__device__ __forceinline__ unsigned short f2bf(float f){
  unsigned u = __float_as_uint(f);
  return (unsigned short)((u + 0x7fffu + ((u >> 16) & 1u)) >> 16);
}
__device__ __forceinline__ unsigned pack2(float a, float b){
  return (unsigned)f2bf(a) | ((unsigned)f2bf(b) << 16);
}
__device__ __forceinline__ float bflo(unsigned u){ return __uint_as_float(u << 16); }
__device__ __forceinline__ float bfhi(unsigned u){ return __uint_as_float(u & 0xffff0000u); }

// cos/sin(2*pi*q/32) for q=0..15
__device__ const float C32C[16] = {
  1.f, 0.98078528f, 0.92387953f, 0.83146961f, 0.70710678f, 0.55557023f,
  0.38268343f, 0.19509032f, 0.f, -0.19509032f, -0.38268343f, -0.55557023f,
  -0.70710678f, -0.83146961f, -0.92387953f, -0.98078528f};
__device__ const float C32S[16] = {
  0.f, 0.19509032f, 0.38268343f, 0.55557023f, 0.70710678f, 0.83146961f,
  0.92387953f, 0.98078528f, 1.f, 0.98078528f, 0.92387953f, 0.83146961f,
  0.70710678f, 0.55557023f, 0.38268343f, 0.19509032f};

// fast exact-enough GELU: Abramowitz-Stegun 7.1.26 erf (max err 1.5e-7)
__device__ __forceinline__ float gelu_fast(float v){
  float x  = v * 0.70710678118654752440f;
  float ax = fabsf(x);
  float t  = __builtin_amdgcn_rcpf(fmaf(0.3275911f, ax, 1.0f));
  float p  = fmaf(fmaf(fmaf(fmaf(1.061405429f, t, -1.453152027f), t,
                            1.421413741f), t, -0.284496736f), t, 0.254829592f);
  float e  = __expf(-x * x);
  float erf_ax = fmaf(-p * t, e, 1.0f);
  float erfx = copysignf(erf_ax, x);
  return 0.5f * v * (1.0f + erfx);
}

// ---------------- complex helpers ----------------
__device__ __forceinline__ float2 cadd(float2 a, float2 b){ return make_float2(a.x+b.x, a.y+b.y); }
__device__ __forceinline__ float2 csub(float2 a, float2 b){ return make_float2(a.x-b.x, a.y-b.y); }
__device__ __forceinline__ float2 cmul(float2 a, float2 b){
  return make_float2(fmaf(a.x, b.x, -(a.y*b.y)), fmaf(a.x, b.y, a.y*b.x));
}

// ---------------- transpose 1: x [B][N][C] fp32 -> xt [B][C][N] bf16 ----------------
__global__ __launch_bounds__(256) void transpose_in_k(const float* __restrict__ in,
                                                      unsigned* __restrict__ out){
  __shared__ float tile[64][33];
  int b  = blockIdx.z;
  int c0 = blockIdx.x * 32;
  int n0 = blockIdx.y * 64;
  int t  = threadIdx.x;
  int tx = t & 31, ty = t >> 5;
  const float* src = in + ((size_t)b * NLEN + n0) * CC + c0;
  #pragma unroll
  for (int k = 0; k < 8; ++k)
    tile[ty + 8*k][tx] = src[(size_t)(ty + 8*k) * CC + tx];
  __syncthreads();
  int lt = t & 15;
  int nl = 4 * lt;
  #pragma unroll
  for (int kk = 0; kk < 2; ++kk){
    int cl = (t >> 4) + 16*kk;
    uint2 u;
    u.x = pack2(tile[nl    ][cl], tile[nl + 1][cl]);
    u.y = pack2(tile[nl + 2][cl], tile[nl + 3][cl]);
    *(uint2*)(out + ((size_t)(b * CC + c0 + cl) * NLEN + n0) / 2 + 2*lt) = u;
  }
}

// ---------------- transpose 2: yt [B][C][N] bf16 -> out [B][N][C] fp32 ----------------
__global__ __launch_bounds__(256) void transpose_out_k(const unsigned* __restrict__ in,
                                                       float* __restrict__ out){
  __shared__ float tile[64][33];
  int b  = blockIdx.z;
  int c0 = blockIdx.x * 32;
  int n0 = blockIdx.y * 64;
  int t  = threadIdx.x;
  int lt = t & 15;
  int nl = 4 * lt;
  #pragma unroll
  for (int kk = 0; kk < 2; ++kk){
    int cl = (t >> 4) + 16*kk;
    uint2 u = *(const uint2*)(in + ((size_t)(b * CC + c0 + cl) * NLEN + n0) / 2 + 2*lt);
    tile[nl    ][cl] = bflo(u.x);
    tile[nl + 1][cl] = bfhi(u.x);
    tile[nl + 2][cl] = bflo(u.y);
    tile[nl + 3][cl] = bfhi(u.y);
  }
  __syncthreads();
  int tx = t & 31, ty = t >> 5;
  float* dst = out + ((size_t)b * NLEN + n0) * CC + c0;
  #pragma unroll
  for (int k = 0; k < 8; ++k)
    dst[(size_t)(ty + 8*k) * CC + tx] = tile[ty + 8*k][tx];
}

// ================= radix-16 register FFT (N=4096, 256 threads, 3 passes) =================
#define SL(e) ((e) + ((e) >> 4))
#define PERM16(p) ((((p) & 3) << 2) | ((p) >> 2))   // X[p] lives in v[PERM16(p)] after dft16ip

template<int SIGN>
__device__ __forceinline__ void dft4ip(float2& v0, float2& v1, float2& v2, float2& v3){
  float2 s02 = cadd(v0, v2), d02 = csub(v0, v2);
  float2 s13 = cadd(v1, v3), d13 = csub(v1, v3);
  float2 id = make_float2(-(float)SIGN * d13.y, (float)SIGN * d13.x);
  v0 = cadd(s02, s13);
  v1 = cadd(d02, id);
  v2 = csub(s02, s13);
  v3 = csub(d02, id);
}

template<int SIGN>
__device__ __forceinline__ float2 w16c(int m){   // e^{SIGN*2pi*i*m/16}
  const float c1 = 0.9238795325112867f, s1 = 0.3826834323650898f, r = 0.7071067811865476f;
  float cs = 1.f, sn = 0.f;
  if (m == 1){ cs = c1;  sn = s1; }
  else if (m == 2){ cs = r;   sn = r; }
  else if (m == 3){ cs = s1;  sn = c1; }
  else if (m == 4){ cs = 0.f; sn = 1.f; }
  else if (m == 6){ cs = -r;  sn = r; }
  else if (m == 9){ cs = -c1; sn = -s1; }
  return make_float2(cs, (float)SIGN * sn);
}

template<int SIGN>
__device__ __forceinline__ void dft16ip(float2 v[16]){
  #pragma unroll
  for (int q0 = 0; q0 < 4; ++q0) dft4ip<SIGN>(v[q0], v[q0+4], v[q0+8], v[q0+12]);
  #pragma unroll
  for (int p0 = 0; p0 < 4; ++p0)
    #pragma unroll
    for (int q0 = 0; q0 < 4; ++q0){
      const int m = p0 * q0;
      if (m) v[q0 + 4*p0] = cmul(v[q0 + 4*p0], w16c<SIGN>(m));
    }
  #pragma unroll
  for (int p0 = 0; p0 < 4; ++p0) dft4ip<SIGN>(v[4*p0], v[4*p0+1], v[4*p0+2], v[4*p0+3]);
}

// 1 sincos + log-depth power tree
template<int SIGN>
__device__ __forceinline__ void twiddle16(float2 v[16], int jm, float invRNs){
  float ang = (float)SIGN * 6.2831853071795864769f * (float)jm * invRNs;
  float sn, cs; __sincosf(ang, &sn, &cs);
  float2 tw[16];
  tw[1] = make_float2(cs, sn);
  #pragma unroll
  for (int q = 2; q < 16; ++q) tw[q] = cmul(tw[q >> 1], tw[q - (q >> 1)]);
  #pragma unroll
  for (int q = 1; q < 16; ++q) v[q] = cmul(v[q], tw[q]);
}

template<int SIGN, int NS>
__device__ __forceinline__ void fft_mid_pass(float2* lds2, float2 v[16], int t){
  #pragma unroll
  for (int q = 0; q < 16; ++q) v[q] = lds2[SL(t + 256*q)];
  int jm = t & (NS - 1);
  if (NS > 1) twiddle16<SIGN>(v, jm, 1.0f / (16.0f * (float)NS));   // NS==1: twiddle == 1
  dft16ip<SIGN>(v);
  __syncthreads();
  int base = ((t - jm) << 4) + jm;
  #pragma unroll
  for (int p = 0; p < 16; ++p) lds2[SL(base + p*NS)] = v[PERM16(p)];
  __syncthreads();
}

#define ORTHO_S 0.011048543456039806f   // 1/sqrt(8192)

// ---------------- forward rfft-8192: xt bf16 row -> tile-blocked spec bins ----------------
__global__ __launch_bounds__(256) void fft_fwd_k(const unsigned* __restrict__ xt,
                                                 unsigned* __restrict__ spec){
  __shared__ float2 lds2[4352];
  int t = threadIdx.x;
  size_t row = blockIdx.x;
  const unsigned* src = xt + row * (NLEN/2);
  float2 v[16];
  #pragma unroll
  for (int q = 0; q < 16; ++q){
    unsigned u = src[t + 256*q];
    v[q] = make_float2(bflo(u), bfhi(u));   // z[m] = x[2m] + i x[2m+1]
  }
  dft16ip<-1>(v);
  #pragma unroll
  for (int p = 0; p < 16; ++p) lds2[SL(16*t + p)] = v[PERM16(p)];
  __syncthreads();
  fft_mid_pass<-1, 16 >(lds2, v, t);
  fft_mid_pass<-1, 256>(lds2, v, t);
  // Hermitian-pair unpack into tile-blocked layout
  unsigned* dst = spec + (row >> 6) * (size_t)BHSZ + (row & 63) * 64;
  float snb, csb;
  __sincosf(-6.2831853071795864769f * (float)t / (float)NLEN, &snb, &csb);
  #pragma unroll
  for (int q = 0; q < 8; ++q){
    int k = t + 256*q;                       // [0, 2048)
    float2 zk = lds2[SL(k)];
    float2 zc = lds2[SL((MH - k) & (MH - 1))];
    float ex = 0.5f*(zk.x + zc.x);
    float ey = 0.5f*(zk.y - zc.y);
    float ox =  0.5f*(zk.y + zc.y);
    float oy = -0.5f*(zk.x - zc.x);
    float cs = fmaf(csb, C32C[q],  snb*C32S[q]);
    float sn = fmaf(snb, C32C[q], -csb*C32S[q]);
    float P = cs*ox - sn*oy;
    float Q = cs*oy + sn*ox;
    dst[KADDR(k)]      = pack2(ORTHO_S*(ex + P), ORTHO_S*(ey + Q));
    dst[KADDR(MH - k)] = pack2(ORTHO_S*(ex - P), ORTHO_S*(Q - ey));  // k=0 -> Nyquist 4096
  }
  if (t == 0){                               // self-dual bin 2048: X = (Zx, -Zy)
    float2 zm = lds2[SL(2048)];
    dst[KADDR(2048)] = pack2(ORTHO_S*zm.x, -ORTHO_S*zm.y);
  }
}

// ---------------- inverse rfft-8192: tile-blocked spec bins -> yt bf16 row ----------------
__global__ __launch_bounds__(256) void fft_inv_k(const unsigned* __restrict__ spec,
                                                 unsigned* __restrict__ yt){
  __shared__ float2 lds2[4352];
  int t = threadIdx.x;
  size_t row = blockIdx.x;
  const unsigned* src = spec + (row >> 6) * (size_t)BHSZ + (row & 63) * 64;
  float snb, csb;
  __sincosf(6.2831853071795864769f * (float)t / (float)NLEN, &snb, &csb);
  #pragma unroll
  for (int q = 0; q < 8; ++q){
    int k = t + 256*q;                       // [0, 2048)
    unsigned uk = src[KADDR(k)];
    unsigned uc = src[KADDR(MH - k)];        // k=0 -> Nyquist bin 4096
    float2 xk = make_float2(bflo(uk), bfhi(uk));
    float2 xc = make_float2(bflo(uc), bfhi(uc));
    if (k == 0){ xk.y = 0.0f; xc.y = 0.0f; } // drop imag at DC/Nyquist
    float ex = xk.x + xc.x;
    float ey = xk.y - xc.y;
    float dx = xk.x - xc.x;
    float dy = xk.y + xc.y;
    float cs = fmaf(csb, C32C[q], -snb*C32S[q]);
    float sn = fmaf(snb, C32C[q],  csb*C32S[q]);
    float ox = cs*dx - sn*dy;
    float oy = cs*dy + sn*dx;
    lds2[SL(k)] = make_float2(ex - oy, ey + ox);          // Z[k] = E + iO
    if (k > 0)
      lds2[SL(MH - k)] = make_float2(ex + oy, ox - ey);   // Z[4096-k] = conj(E - iO)
  }
  if (t == 0){                               // self-dual m=2048: Z = 2*conj(X[2048])
    unsigned um = src[KADDR(2048)];
    lds2[SL(2048)] = make_float2(2.0f*bflo(um), -2.0f*bfhi(um));
  }
  __syncthreads();
  float2 v[16];
  fft_mid_pass<1, 1  >(lds2, v, t);          // pass 1 (no twiddle)
  fft_mid_pass<1, 16 >(lds2, v, t);
  fft_mid_pass<1, 256>(lds2, v, t);
  // wide-store epilogue
  uint4* d4 = (uint4*)(yt + row * (NLEN/2) + 16*t);
  #pragma unroll
  for (int g = 0; g < 4; ++g){
    float2 w0 = lds2[SL(16*t + 4*g    )];
    float2 w1 = lds2[SL(16*t + 4*g + 1)];
    float2 w2 = lds2[SL(16*t + 4*g + 2)];
    float2 w3 = lds2[SL(16*t + 4*g + 3)];
    uint4 stv;
    stv.x = pack2(ORTHO_S*w0.x, ORTHO_S*w0.y);
    stv.y = pack2(ORTHO_S*w1.x, ORTHO_S*w1.y);
    stv.z = pack2(ORTHO_S*w2.x, ORTHO_S*w2.y);
    stv.w = pack2(ORTHO_S*w3.x, ORTHO_S*w3.y);
    d4[g] = stv;
  }
}

// ---------------- weight prep: transpose + bf16 + swizzle (+pi for W2) ----------------
__global__ __launch_bounds__(256) void wprep_k(const float* __restrict__ w1,
                                               const float* __restrict__ w2){
  int t = threadIdx.x;
  int h = blockIdx.x;
  #pragma unroll 4
  for (int u = 0; u < 64; ++u){
    int idx = t + 256*u;          // p*4096 + o*64 + jj
    int p = idx >> 12;
    int o = (idx >> 6) & 63;
    int jj = idx & 63;
    int swo = (o ^ (o >> 3)) & 7;
    int s = (((jj >> 3) ^ swo) << 3) | (jj & 7);   // linear k-slot
    int i;
    if (p < 2){
      i = s;
    } else {
      int ks = s >> 5, g = (s >> 3) & 3, j = s & 7;
      i = (2*ks + (j >> 2))*16 + 4*g + (j & 3);
    }
    const float* src = (p < 2) ? w1 : w2;
    float v = src[(size_t)(p & 1) * 32768 + (size_t)h * 4096 + i * 64 + o];
    g_wprep[(size_t)h * 16384 + idx] = f2bf(v);
  }
}

// ---------------- middle: MFMA MLP on contiguous 16KB X tiles, W in LDS ----------------
__global__ __launch_bounds__(256) void afno_mid_mfma_k(const unsigned* __restrict__ spec_in,
                                                       unsigned* __restrict__ spec_out,
                                                       const float* __restrict__ b1,
                                                       const float* __restrict__ b2){
  __shared__ unsigned short Wl[16384];                   // 4 planes x 64 x 64 bf16
  const int t = threadIdx.x;
  const int bx = blockIdx.x, h = blockIdx.y, b = blockIdx.z;
  const size_t bhoff = (size_t)(b * HH + h) * BHSZ + (size_t)bx * 4096;
  const int l = t & 63, wv = t >> 6;
  const int lf = l & 15, lg = l >> 4;
  const int wf0 = wv * 16;

  // ---- issue X fragment loads FIRST from the contiguous tile ----
  const unsigned* xblk = spec_in + bhoff;
  unsigned bins[16];
  #pragma unroll
  for (int ks = 0; ks < 2; ++ks){
    int i0 = (ks*4 + lg) * 8;
    #pragma unroll
    for (int j = 0; j < 8; ++j)
      bins[ks*8 + j] = xblk[(i0 + j)*64 + wf0 + lf];
  }

  // ---- stage W once (32KB linear copy) ----
  {
    const uint4* gw  = (const uint4*)(g_wprep + (size_t)h * 16384);
    uint4*       sw4 = (uint4*)Wl;
    #pragma unroll
    for (int u = 0; u < 8; ++u) sw4[t + 256*u] = gw[t + 256*u];
  }
  // ---- hoist biases ----
  float4 br1[4], bi1[4];
  #pragma unroll
  for (int mt = 0; mt < 4; ++mt){
    br1[mt] = *(const float4*)(b1 +       (size_t)h*64 + mt*16 + lg*4);
    bi1[mt] = *(const float4*)(b1 + 512 + (size_t)h*64 + mt*16 + lg*4);
  }
  float b2r[4], b2i[4];
  #pragma unroll
  for (int nt = 0; nt < 4; ++nt){
    b2r[nt] = b2[(size_t)h*64 + nt*16 + lf];
    b2i[nt] = b2[512 + (size_t)h*64 + nt*16 + lf];
  }
  __syncthreads();                                       // W ready

  const unsigned short* W1R = Wl;
  const unsigned short* W1I = Wl + 4096;
  const unsigned short* W2R = Wl + 8192;
  const unsigned short* W2I = Wl + 12288;
  const f32x4 zz = {0.f, 0.f, 0.f, 0.f};

  f32x4 a1R[4], a1I[4];
  #pragma unroll
  for (int mt = 0; mt < 4; ++mt){ a1R[mt] = zz; a1I[mt] = zz; }

  // -------- stage 1: O1^T = W1^T X^T --------
  #pragma unroll
  for (int ks = 0; ks < 2; ++ks){
    u32x4 pr, pi;
    pr.x = __builtin_amdgcn_perm(bins[ks*8+1], bins[ks*8+0], 0x05040100u);
    pr.y = __builtin_amdgcn_perm(bins[ks*8+3], bins[ks*8+2], 0x05040100u);
    pr.z = __builtin_amdgcn_perm(bins[ks*8+5], bins[ks*8+4], 0x05040100u);
    pr.w = __builtin_amdgcn_perm(bins[ks*8+7], bins[ks*8+6], 0x05040100u);
    pi.x = __builtin_amdgcn_perm(bins[ks*8+1], bins[ks*8+0], 0x07060302u);
    pi.y = __builtin_amdgcn_perm(bins[ks*8+3], bins[ks*8+2], 0x07060302u);
    pi.z = __builtin_amdgcn_perm(bins[ks*8+5], bins[ks*8+4], 0x07060302u);
    pi.w = __builtin_amdgcn_perm(bins[ks*8+7], bins[ks*8+6], 0x07060302u);
    bf16x8 bxr = __builtin_bit_cast(bf16x8, pr);
    bf16x8 bxi = __builtin_bit_cast(bf16x8, pi);
    int b0 = ks*4 + lg;
    #pragma unroll
    for (int mt = 0; mt < 4; ++mt){
      int o = mt*16 + lf;
      int swo = (o ^ (o >> 3)) & 7;
      int off = o*64 + ((b0 ^ swo) << 3);
      bf16x8 awr  = *(const bf16x8*)(W1R + off);
      bf16x8 awi  = *(const bf16x8*)(W1I + off);
      bf16x8 awin = awi ^ (short)0x8000;
      a1R[mt] = MFMA(awr,  bxr, a1R[mt]);
      a1R[mt] = MFMA(awin, bxi, a1R[mt]);
      a1I[mt] = MFMA(awi,  bxr, a1I[mt]);
      a1I[mt] = MFMA(awr,  bxi, a1I[mt]);
    }
  }

  // -------- stage-1 epilogue: bias + GELU -> stage-2 A-fragments --------
  bf16x8 aFr[2], aFi[2], aFin[2];
  #pragma unroll
  for (int ks = 0; ks < 2; ++ks){
    const int m0 = 2*ks, m1 = 2*ks + 1;
    u32x4 wr4, wi4;
    wr4.x = pack2(gelu_fast(a1R[m0][0] + br1[m0].x), gelu_fast(a1R[m0][1] + br1[m0].y));
    wr4.y = pack2(gelu_fast(a1R[m0][2] + br1[m0].z), gelu_fast(a1R[m0][3] + br1[m0].w));
    wr4.z = pack2(gelu_fast(a1R[m1][0] + br1[m1].x), gelu_fast(a1R[m1][1] + br1[m1].y));
    wr4.w = pack2(gelu_fast(a1R[m1][2] + br1[m1].z), gelu_fast(a1R[m1][3] + br1[m1].w));
    wi4.x = pack2(gelu_fast(a1I[m0][0] + bi1[m0].x), gelu_fast(a1I[m0][1] + bi1[m0].y));
    wi4.y = pack2(gelu_fast(a1I[m0][2] + bi1[m0].z), gelu_fast(a1I[m0][3] + bi1[m0].w));
    wi4.z = pack2(gelu_fast(a1I[m1][0] + bi1[m1].x), gelu_fast(a1I[m1][1] + bi1[m1].y));
    wi4.w = pack2(gelu_fast(a1I[m1][2] + bi1[m1].z), gelu_fast(a1I[m1][3] + bi1[m1].w));
    aFr[ks]  = __builtin_bit_cast(bf16x8, wr4);
    aFi[ks]  = __builtin_bit_cast(bf16x8, wi4);
    aFin[ks] = aFi[ks] ^ (short)0x8000;
  }

  // -------- stage 2: O2 = O1 W2 --------
  f32x4 a2R[4], a2I[4];
  #pragma unroll
  for (int nt = 0; nt < 4; ++nt){ a2R[nt] = zz; a2I[nt] = zz; }
  #pragma unroll
  for (int ks = 0; ks < 2; ++ks){
    int b0 = ks*4 + lg;
    #pragma unroll
    for (int nt = 0; nt < 4; ++nt){
      int o2 = nt*16 + lf;
      int swo = (o2 ^ (o2 >> 3)) & 7;
      int off = o2*64 + ((b0 ^ swo) << 3);
      bf16x8 bwr = *(const bf16x8*)(W2R + off);
      bf16x8 bwi = *(const bf16x8*)(W2I + off);
      a2R[nt] = MFMA(aFr[ks],  bwr, a2R[nt]);
      a2R[nt] = MFMA(aFin[ks], bwi, a2R[nt]);
      a2I[nt] = MFMA(aFi[ks],  bwr, a2I[nt]);
      a2I[nt] = MFMA(aFr[ks],  bwi, a2I[nt]);
    }
  }

  // -------- stage-2 epilogue: bias + contiguous 16B tile stores (no mask) --------
  unsigned* oblk = spec_out + bhoff;
  int fl0 = wf0 + lg*4;
  #pragma unroll
  for (int nt = 0; nt < 4; ++nt){
    int o2 = nt*16 + lf;
    uint4 st;
    st.x = pack2(a2R[nt][0] + b2r[nt], a2I[nt][0] + b2i[nt]);
    st.y = pack2(a2R[nt][1] + b2r[nt], a2I[nt][1] + b2i[nt]);
    st.z = pack2(a2R[nt][2] + b2r[nt], a2I[nt][2] + b2i[nt]);
    st.w = pack2(a2R[nt][3] + b2r[nt], a2I[nt][3] + b2i[nt]);
    *(uint4*)(oblk + o2*64 + fl0) = st;
  }
}

// ---------------- launch ----------------
extern "C" void kernel_launch(void* const* d_in, const int* in_sizes, int n_in,
                              void* d_out, int out_size, void* d_ws, size_t ws_size,
                              hipStream_t stream) {
  const float* x  = (const float*)d_in[0];
  const float* w1 = (const float*)d_in[1];
  const float* b1 = (const float*)d_in[2];
  const float* w2 = (const float*)d_in[3];
  const float* b2 = (const float*)d_in[4];
  float* out = (float*)d_out;

  unsigned char* base = (unsigned char*)d_ws;
  if (ws_size < 2 * REGION_BYTES){
    void* p = nullptr;
    hipGetSymbolAddress(&p, HIP_SYMBOL(g_scratch));
    base = (unsigned char*)p;
  }
  unsigned* specA = (unsigned*)base;                 // region A: spectrum1, later yt
  unsigned char* regB = base + REGION_BYTES;         // region B: xt, later spectrum2
  unsigned* xt    = (unsigned*)regB;
  unsigned* specB = (unsigned*)regB;
  unsigned* ytp   = (unsigned*)base;

  // 0) weight prep (bf16 + transpose + swizzle + stage-2 pi)
  wprep_k<<<8, 256, 0, stream>>>(w1, w2);
  // 1) transpose x [B][N][C] fp32 -> xt [B][C][N] bf16
  transpose_in_k<<<dim3(CC/32, NLEN/64, BB), 256, 0, stream>>>(x, xt);
  // 2) forward rfft per row -> tile-blocked spectrum
  fft_fwd_k<<<NSEQ, 256, 0, stream>>>(xt, specA);
  // 3) complex MLP on contiguous 16KB tiles (bf16 MFMA)
  afno_mid_mfma_k<<<dim3(65, HH, BB), 256, 0, stream>>>(specA, specB, b1, b2);
  // 4) inverse rfft per row from tile-blocked spectrum
  fft_inv_k<<<NSEQ, 256, 0, stream>>>(specB, ytp);
  // 5) transpose yt [B][C][N] bf16 -> out [B][N][C] fp32
  transpose_out_k<<<dim3(CC/32, NLEN/64, BB), 256, 0, stream>>>(ytp, out);
}